// Round 9
// baseline (8074.382 us; speedup 1.0000x reference)
//
#include <hip/hip_runtime.h>
#include <hip/hip_bf16.h>

#define H_DIM 1024
#define B_DIM 64
#define T_DIM 512
#define I_PAD 128
#define I_ORIG 118
#define FC_DIM 16
#define HB (B_DIM * H_DIM)

typedef __hip_bfloat16 bf16;
typedef __attribute__((ext_vector_type(8))) short short8v;
typedef __attribute__((ext_vector_type(4))) float f32x4;

#define MFMA16(a, b, c) __builtin_amdgcn_mfma_f32_16x16x32_bf16(a, b, c, 0, 0, 0)

__device__ __forceinline__ short8v ldg8(const bf16* p) {
    return *reinterpret_cast<const short8v*>(p);
}
__device__ __forceinline__ short8v ld_byp16(const bf16* p) {
    union { unsigned long long u[2]; short8v v; } r;
    const unsigned long long* q = reinterpret_cast<const unsigned long long*>(p);
    r.u[0] = __hip_atomic_load(q,     __ATOMIC_RELAXED, __HIP_MEMORY_SCOPE_AGENT);
    r.u[1] = __hip_atomic_load(q + 1, __ATOMIC_RELAXED, __HIP_MEMORY_SCOPE_AGENT);
    return r.v;
}
__device__ __forceinline__ unsigned short f2bf_bits(float f) {
    union { bf16 h; unsigned short s; } u;
    u.h = __float2bfloat16(f);
    return u.s;
}
__device__ __forceinline__ void st_coh(unsigned* p, unsigned v) {
    __hip_atomic_store(p, v, __ATOMIC_RELAXED, __HIP_MEMORY_SCOPE_AGENT);
}
__device__ __forceinline__ unsigned long long ld_coh64(const unsigned long long* p) {
    return __hip_atomic_load(p, __ATOMIC_RELAXED, __HIP_MEMORY_SCOPE_AGENT);
}

// ---------------------------------------------------------------------------
// x[b][t][i] f32 -> x_bf[t][b][c] bf16 (c padded 118->128 with zeros)
// ---------------------------------------------------------------------------
__global__ __launch_bounds__(256) void cvt_x_kernel(
    const float* __restrict__ x, bf16* __restrict__ out)
{
    int idx  = blockIdx.x * 256 + threadIdx.x;
    int c    = idx & 127;
    int rest = idx >> 7;
    int b    = rest & 63;
    int t    = rest >> 6;
    float v  = (c < I_ORIG) ? x[((long)b * T_DIM + t) * I_ORIG + c] : 0.0f;
    out[idx] = __float2bfloat16(v);
}

__global__ __launch_bounds__(256) void cvt_pad(
    const float* __restrict__ in, bf16* __restrict__ out,
    int kin, int kp, long total)
{
    long idx = (long)blockIdx.x * 256 + threadIdx.x;
    if (idx >= total) return;
    int  c = (int)(idx % kp);
    long r = idx / kp;
    out[idx] = __float2bfloat16(c < kin ? in[r * kin + c] : 0.0f);
}

// ---------------------------------------------------------------------------
// FUSED two-layer encoder. grid 256 x 256 threads, 1 block/CU.
//   lyr = bid>>7 (0: layer1, 1: layer2), mh = (bid>>6)&1 (batch rows 32mh..+32),
//   bn = bid&63 (j-tile of 16). Waves: ms = w>>1 (m-sub 16), kh = w&1 (k-half 512).
// BIAS RULE: only the kh==0 wave's accumulators carry the bias (the LDS
// reduce sums both k-halves; R8 double-counted it).
// Layer 1 step t: reads h1(t-1) = h1all slot t (cached; write-once slots),
//   writes h1(t) -> slot t+1 (sc1), flag L1=t+1 (always, layer2 needs t=511).
// Layer 2 step t: polls {L1 flag >= t+1, L2 flag >= t} (one 8B load/lane),
//   input A = h1all slot t+1 (cached), hidden A = h2pp slot t&1 (bypass),
//   writes h2(t) -> h2pp slot (t+1)&1 (sc1), flag L2=t+1.
// Flags: [mh][bn][wave][layer] dwords -> consumer reads dword-pairs.
// Overwrite safety: union of the 4 waves' polls covers all 64 same-(mh,lyr)
// blocks x 4 waves, and stores happen after the block-wide reduce barrier.
// ---------------------------------------------------------------------------
__global__ __launch_bounds__(256, 1) void gru_fused(
    const bf16* __restrict__ x_bf,
    const bf16* __restrict__ Wx1, const bf16* __restrict__ Wh1,
    const bf16* __restrict__ Wx2, const bf16* __restrict__ Wh2,
    const float* __restrict__ bih1, const float* __restrict__ bhh1,
    const float* __restrict__ bih2, const float* __restrict__ bhh2,
    bf16* h1all, bf16* h2pp,
    float* hf1f, float* hf2f,
    unsigned* flags)
{
    extern __shared__ char smem[];
    constexpr int WH = 98304;              // 48 rows x 2048B (Whh slice)
    constexpr int WX = 12288;              // 48 rows x 256B  (Wx1 slice, layer1)
    constexpr int REDF = 4352;             // floats per red buffer (16 tiles x 272)
    float* redbase = (float*)(smem + WH + WX);

    const int tid  = threadIdx.x;
    const int w    = tid >> 6;
    const int lane = tid & 63;
    const int ln   = lane & 15;
    const int lk   = lane >> 4;
    const int bid  = blockIdx.x;
    const int lyr  = bid >> 7;
    const int mh   = (bid >> 6) & 1;
    const int bn   = bid & 63;
    const int ms   = w >> 1;
    const int kh   = w & 1;
    const int j0   = bn << 4;
    const int m0   = mh << 5;
    const int j    = j0 + ln;

    // ---- stage Whh slice (swizzled rows of 2048B)
    const bf16* WhG = lyr ? Wh2 : Wh1;
    for (int c = tid; c < WH / 16; c += 256) {
        int lin = c * 16;
        int row = lin >> 11;
        int wb  = lin & 2047;
        int g   = row >> 4, jj = row & 15;
        const bf16* src = WhG + ((long)(g * 1024 + j0 + jj) << 10) + (wb >> 1);
        *reinterpret_cast<short8v*>(smem + (lin ^ ((jj & 7) << 4))) = ldg8(src);
    }
    if (lyr == 0) {
        for (int c = tid; c < WX / 16; c += 256) {
            int lin = c * 16;
            int row = lin >> 8;
            int wb  = lin & 255;
            int g   = row >> 4, jj = row & 15;
            const bf16* src = Wx1 + (long)(g * 1024 + j0 + jj) * I_PAD + (wb >> 1);
            *reinterpret_cast<short8v*>(smem + WH + (lin ^ ((jj & 7) << 4))) = ldg8(src);
        }
    }
    __syncthreads();

    const float* bihv = lyr ? bih2 : bih1;
    const float* bhhv = lyr ? bhh2 : bhh1;
    const float kb   = (kh == 0) ? 1.0f : 0.0f;        // bias once across k-halves
    const float b_r  = (bihv[j] + bhhv[j]) * kb;
    const float b_z  = (bihv[j + 1024] + bhhv[j + 1024]) * kb;
    const float b_ni = bihv[j + 2048] * kb;
    const float b_nh = bhhv[j + 2048] * kb;

    const int swz  = (ln & 7) << 4;
    const int whb0 = ln * 2048 + kh * 1024 + lk * 16;   // + ks*64; gates +32768/+65536
    const int wxb0 = WH + ln * 256 + kh * 128 + lk * 16;
    const long arow = m0 + (ms << 4) + ln;              // A-fragment row
    const int  rl0  = (w << 3) + lk;                    // combine rows rl0, rl0+4
    const int  tgrp = ((ms << 1) | kh) << 2;            // red tile base

    const unsigned long long* pollp =
        (const unsigned long long*)flags +
        ((mh << 8) | (((kh << 5) | (lane & 31)) << 2) | ((ms << 1) | (lane >> 5)));
    unsigned* myflag = flags + ((((mh << 8) | (bn << 2) | w) << 1) | lyr);

    float hp0 = 0.0f, hp1 = 0.0f;     // register-carried f32 h for combine rows

    if (lyr == 0) {
        // =========================== LAYER 1 ===========================
        short8v xc0, xc1;
        {
            const bf16* xr = x_bf + arow * I_PAD + kh * 64 + lk * 8;
            xc0 = ldg8(xr); xc1 = ldg8(xr + 32);
        }
        for (int t = 0; t < T_DIM; ++t) {
            f32x4 aR0{b_r,b_r,b_r,b_r}, aZ0{b_z,b_z,b_z,b_z};
            f32x4 aNI{b_ni,b_ni,b_ni,b_ni}, aNH0{b_nh,b_nh,b_nh,b_nh};
            f32x4 aR1{0,0,0,0}, aZ1{0,0,0,0}, aNH1{0,0,0,0};

            // input-side gates (pre-poll; x ready)
            {
                int o = wxb0;
                short8v br  = *(const short8v*)(smem + ((o       ) ^ swz));
                short8v bz  = *(const short8v*)(smem + ((o + 4096) ^ swz));
                short8v bnn = *(const short8v*)(smem + ((o + 8192) ^ swz));
                aR0 = MFMA16(xc0, br, aR0); aZ0 = MFMA16(xc0, bz, aZ0);
                aNI = MFMA16(xc0, bnn, aNI);
                o = wxb0 + 64;
                br  = *(const short8v*)(smem + ((o       ) ^ swz));
                bz  = *(const short8v*)(smem + ((o + 4096) ^ swz));
                bnn = *(const short8v*)(smem + ((o + 8192) ^ swz));
                aR1 = MFMA16(xc1, br, aR1); aZ1 = MFMA16(xc1, bz, aZ1);
                aNI = MFMA16(xc1, bnn, aNI);
            }

            // poll own-layer flags >= t (low dword of the pair)
            {
                const unsigned tgt = (unsigned)t;
                while (true) {
                    unsigned long long fv = ld_coh64(pollp);
                    if (__all((int)((unsigned)fv >= tgt))) break;
                }
                asm volatile("" ::: "memory");
            }

            // hidden A (cached; write-once slot t) + MFMAs
            const bf16* ha = h1all + (long)t * HB + arow * H_DIM + kh * 512 + lk * 8;
            short8v ah[16];
#pragma unroll
            for (int ks = 0; ks < 16; ++ks) ah[ks] = ldg8(ha + ks * 32);
#pragma unroll
            for (int ks = 0; ks < 16; ++ks) {
                int o = whb0 + ks * 64;
                short8v br  = *(const short8v*)(smem + ((o        ) ^ swz));
                short8v bz  = *(const short8v*)(smem + ((o + 32768) ^ swz));
                short8v bnn = *(const short8v*)(smem + ((o + 65536) ^ swz));
                if (ks & 1) { aR1 = MFMA16(ah[ks], br, aR1); aZ1 = MFMA16(ah[ks], bz, aZ1); aNH1 = MFMA16(ah[ks], bnn, aNH1); }
                else        { aR0 = MFMA16(ah[ks], br, aR0); aZ0 = MFMA16(ah[ks], bz, aZ0); aNH0 = MFMA16(ah[ks], bnn, aNH0); }
            }
            f32x4 vR = aR0 + aR1, vZ = aZ0 + aZ1, vNH = aNH0 + aNH1, vNI = aNI;

            // K-half partials to LDS (17-padded rows, dbuf)
            float* red = redbase + (t & 1) * REDF;
#pragma unroll
            for (int a = 0; a < 4; ++a) {
                f32x4 v = (a == 0) ? vR : (a == 1) ? vZ : (a == 2) ? vNI : vNH;
                int base = (tgrp + a) * 272 + (lk << 2) * 17 + ln;
#pragma unroll
                for (int e = 0; e < 4; ++e) red[base + e * 17] = v[e];
            }
            __syncthreads();

            // combine (2 rows/lane) + store + flag
            float hv0, hv1;
#pragma unroll
            for (int e2 = 0; e2 < 2; ++e2) {
                int rl = rl0 + (e2 << 2);
                int msrc = rl >> 4, rr = rl & 15;
                int b0 = (msrc << 3) * 272 + rr * 17 + ln;
                int b1 = b0 + 4 * 272;
                float sR  = red[b0] + red[b1];
                float sZ  = red[b0 + 272] + red[b1 + 272];
                float sNI = red[b0 + 544] + red[b1 + 544];
                float sNH = red[b0 + 816] + red[b1 + 816];
                float rr_ = 1.0f / (1.0f + __expf(-sR));
                float zz  = 1.0f / (1.0f + __expf(-sZ));
                float xn  = sNI + rr_ * sNH;
                float nn  = 2.0f / (1.0f + __expf(-2.0f * xn)) - 1.0f;
                float hp  = e2 ? hp1 : hp0;
                float hv  = (1.0f - zz) * nn + zz * hp;
                if (e2) { hp1 = hv; hv1 = hv; } else { hp0 = hv; hv0 = hv; }
            }
            bf16* outslot = h1all + (long)(t + 1) * HB;
            float ho0 = __shfl_xor(hv0, 1), ho1 = __shfl_xor(hv1, 1);
            if ((ln & 1) == 0) {
                unsigned p0 = (unsigned)f2bf_bits(hv0) | ((unsigned)f2bf_bits(ho0) << 16);
                unsigned p1 = (unsigned)f2bf_bits(hv1) | ((unsigned)f2bf_bits(ho1) << 16);
                st_coh((unsigned*)(outslot + (long)(m0 + rl0) * 1024 + (j & ~1)), p0);
                st_coh((unsigned*)(outslot + (long)(m0 + rl0 + 4) * 1024 + (j & ~1)), p1);
            }
            if (t == T_DIM - 1) {
                hf1f[(long)(m0 + rl0) * 1024 + j] = hv0;
                hf1f[(long)(m0 + rl0 + 4) * 1024 + j] = hv1;
            }
            asm volatile("s_waitcnt vmcnt(0)" ::: "memory");
            if (lane == 0) st_coh(myflag, (unsigned)(t + 1));   // ALWAYS (L2 needs it)
            if (t + 1 < T_DIM) {
                const bf16* xr = x_bf + (long)(t + 1) * (B_DIM * I_PAD)
                               + arow * I_PAD + kh * 64 + lk * 8;
                xc0 = ldg8(xr); xc1 = ldg8(xr + 32);
            }
        }
    } else {
        // =========================== LAYER 2 ===========================
        const bf16* wxr = Wx2 + (long)j * 1024 + kh * 512 + lk * 8;
        for (int t = 0; t < T_DIM; ++t) {
            // poll: L1 flag >= t+1 (h1(t) ready) AND L2 flag >= t (h2(t-1))
            {
                const unsigned t1 = (unsigned)(t + 1), t0 = (unsigned)t;
                while (true) {
                    unsigned long long fv = ld_coh64(pollp);
                    unsigned f1 = (unsigned)fv, f2 = (unsigned)(fv >> 32);
                    if (__all((int)((f1 >= t1) & (f2 >= t0)))) break;
                }
                asm volatile("" ::: "memory");
            }

            // A loads: input h1(t) (cached, write-once) + hidden h2(t-1) (bypass)
            const bf16* xa = h1all + (long)(t + 1) * HB + arow * H_DIM + kh * 512 + lk * 8;
            const bf16* ha = h2pp + (long)(t & 1) * HB + arow * H_DIM + kh * 512 + lk * 8;
            short8v ai[16], ah[16];
#pragma unroll
            for (int ks = 0; ks < 16; ++ks) ai[ks] = ldg8(xa + ks * 32);
#pragma unroll
            for (int ks = 0; ks < 16; ++ks) ah[ks] = ld_byp16(ha + ks * 32);

            f32x4 aR0{b_r,b_r,b_r,b_r}, aZ0{b_z,b_z,b_z,b_z};
            f32x4 aNI0{b_ni,b_ni,b_ni,b_ni}, aNH0{b_nh,b_nh,b_nh,b_nh};
            f32x4 aR1{0,0,0,0}, aZ1{0,0,0,0}, aNI1{0,0,0,0}, aNH1{0,0,0,0};

            // input-side (Wx2 from global, XCD-L2 resident after first steps)
#pragma unroll
            for (int ks = 0; ks < 16; ++ks) {
                short8v br  = ldg8(wxr + ks * 32);
                short8v bz  = ldg8(wxr + (1 << 20) + ks * 32);
                short8v bnn = ldg8(wxr + (2 << 20) + ks * 32);
                if (ks & 1) { aR1 = MFMA16(ai[ks], br, aR1); aZ1 = MFMA16(ai[ks], bz, aZ1); aNI1 = MFMA16(ai[ks], bnn, aNI1); }
                else        { aR0 = MFMA16(ai[ks], br, aR0); aZ0 = MFMA16(ai[ks], bz, aZ0); aNI0 = MFMA16(ai[ks], bnn, aNI0); }
            }
            // hidden-side (Whh from LDS)
#pragma unroll
            for (int ks = 0; ks < 16; ++ks) {
                int o = whb0 + ks * 64;
                short8v br  = *(const short8v*)(smem + ((o        ) ^ swz));
                short8v bz  = *(const short8v*)(smem + ((o + 32768) ^ swz));
                short8v bnn = *(const short8v*)(smem + ((o + 65536) ^ swz));
                if (ks & 1) { aR1 = MFMA16(ah[ks], br, aR1); aZ1 = MFMA16(ah[ks], bz, aZ1); aNH1 = MFMA16(ah[ks], bnn, aNH1); }
                else        { aR0 = MFMA16(ah[ks], br, aR0); aZ0 = MFMA16(ah[ks], bz, aZ0); aNH0 = MFMA16(ah[ks], bnn, aNH0); }
            }
            f32x4 vR = aR0 + aR1, vZ = aZ0 + aZ1, vNI = aNI0 + aNI1, vNH = aNH0 + aNH1;

            float* red = redbase + (t & 1) * REDF;
#pragma unroll
            for (int a = 0; a < 4; ++a) {
                f32x4 v = (a == 0) ? vR : (a == 1) ? vZ : (a == 2) ? vNI : vNH;
                int base = (tgrp + a) * 272 + (lk << 2) * 17 + ln;
#pragma unroll
                for (int e = 0; e < 4; ++e) red[base + e * 17] = v[e];
            }
            __syncthreads();

            float hv0, hv1;
#pragma unroll
            for (int e2 = 0; e2 < 2; ++e2) {
                int rl = rl0 + (e2 << 2);
                int msrc = rl >> 4, rr = rl & 15;
                int b0 = (msrc << 3) * 272 + rr * 17 + ln;
                int b1 = b0 + 4 * 272;
                float sR  = red[b0] + red[b1];
                float sZ  = red[b0 + 272] + red[b1 + 272];
                float sNI = red[b0 + 544] + red[b1 + 544];
                float sNH = red[b0 + 816] + red[b1 + 816];
                float rr_ = 1.0f / (1.0f + __expf(-sR));
                float zz  = 1.0f / (1.0f + __expf(-sZ));
                float xn  = sNI + rr_ * sNH;
                float nn  = 2.0f / (1.0f + __expf(-2.0f * xn)) - 1.0f;
                float hp  = e2 ? hp1 : hp0;
                float hv  = (1.0f - zz) * nn + zz * hp;
                if (e2) { hp1 = hv; hv1 = hv; } else { hp0 = hv; hv0 = hv; }
            }
            bf16* outslot = h2pp + (long)((t + 1) & 1) * HB;
            float ho0 = __shfl_xor(hv0, 1), ho1 = __shfl_xor(hv1, 1);
            if ((ln & 1) == 0) {
                unsigned p0 = (unsigned)f2bf_bits(hv0) | ((unsigned)f2bf_bits(ho0) << 16);
                unsigned p1 = (unsigned)f2bf_bits(hv1) | ((unsigned)f2bf_bits(ho1) << 16);
                st_coh((unsigned*)(outslot + (long)(m0 + rl0) * 1024 + (j & ~1)), p0);
                st_coh((unsigned*)(outslot + (long)(m0 + rl0 + 4) * 1024 + (j & ~1)), p1);
            }
            if (t == T_DIM - 1) {
                hf2f[(long)(m0 + rl0) * 1024 + j] = hv0;
                hf2f[(long)(m0 + rl0 + 4) * 1024 + j] = hv1;
            }
            asm volatile("s_waitcnt vmcnt(0)" ::: "memory");
            if (lane == 0) st_coh(myflag, (unsigned)(t + 1));
        }
    }
}

// ---------------------------------------------------------------------------
// Single-step GRU cell (decoder) — R7 kernel, !SEQ variants only.
// ---------------------------------------------------------------------------
template<int WXK, bool WXG, bool SEQ>
__global__ __launch_bounds__(256, 1) void gru_pass(
    const bf16* __restrict__ xbase, long xstride,
    const bf16* __restrict__ WxG,
    const bf16* __restrict__ WhG,
    const float* __restrict__ bih, const float* __restrict__ bhh,
    const bf16* hin, bf16* hout,
    const float* f_init, float* f_final,
    int nsteps, unsigned* flags)
{
    extern __shared__ char smem[];
    constexpr int WH_BYTES = 3 * 16 * 1024 * 2;
    constexpr int WX_BYTES = WXG ? 0 : 3 * 16 * WXK * 2;
    float* sm_red = (float*)(smem + WH_BYTES + WX_BYTES);

    const int tid  = threadIdx.x;
    const int w    = tid >> 6;
    const int lane = tid & 63;
    const int ln   = lane & 15;
    const int lk   = lane >> 4;
    const int bid  = blockIdx.x;
    const int bn   = bid & 63;
    const int grp  = bid >> 6;
    const int j0   = bn * 16;
    const int m0   = grp * 16;
    const int j    = j0 + ln;

    for (int c = tid; c < WH_BYTES / 16; c += 256) {
        int lin = c * 16;
        int row = lin >> 11;
        int wb  = lin & 2047;
        int g   = row >> 4, jj = row & 15;
        const bf16* src = WhG + ((long)(g * 1024 + j0 + jj) << 10) + (wb >> 1);
        *reinterpret_cast<short8v*>(smem + (lin ^ ((jj & 7) << 4))) = ldg8(src);
    }
    if constexpr (!WXG) {
        for (int c = tid; c < WX_BYTES / 16; c += 256) {
            int lin = c * 16;
            int row = lin / (WXK * 2);
            int wb  = lin % (WXK * 2);
            int g   = row >> 4, jj = row & 15;
            const bf16* src = WxG + (long)(g * 1024 + j0 + jj) * WXK + (wb >> 1);
            *reinterpret_cast<short8v*>(smem + WH_BYTES + (lin ^ ((jj & 7) << 4))) = ldg8(src);
        }
    }
    __syncthreads();

    const int wkoh = w << 8;
    const int wkox = (WXK == 128) ? (w << 5) : (w << 8);
    const int swz  = (ln & 7) << 4;
    const int whb0 = ln * 2048 + ((wkoh + lk * 8) << 1);

    const float bias_r  = bih[j] + bhh[j];
    const float bias_z  = bih[j + H_DIM] + bhh[j + H_DIM];
    const float bias_ni = bih[j + 2 * H_DIM];
    const float bias_nh = bhh[j + 2 * H_DIM];

    const int  crow = (w << 2) | lk;
    const int  gm   = m0 + crow;
    const long opos = (long)gm * H_DIM + j;

    float hprev = f_init ? f_init[opos] : 0.0f;

    constexpr int NKX = (WXK == 128) ? 1 : 8;
    short8v xcur[NKX];
    {
        const bf16* xr = xbase + (long)(m0 + ln) * WXK + wkox + lk * 8;
#pragma unroll
        for (int ks = 0; ks < NKX; ++ks) xcur[ks] = ldg8(xr + ks * 32);
    }

    for (int t = 0; t < nsteps; ++t) {
        f32x4 aR{0,0,0,0}, aZ{0,0,0,0}, aNI{0,0,0,0}, aNH{0,0,0,0};

        if constexpr (WXK == 128) {
            int o = WH_BYTES + ln * 256 + ((wkox + lk * 8) << 1);
            short8v br  = *(const short8v*)(smem + ((o       ) ^ swz));
            short8v bz  = *(const short8v*)(smem + ((o + 4096) ^ swz));
            short8v bnn = *(const short8v*)(smem + ((o + 8192) ^ swz));
            aR  = MFMA16(xcur[0], br,  aR);
            aZ  = MFMA16(xcur[0], bz,  aZ);
            aNI = MFMA16(xcur[0], bnn, aNI);
        } else {
            const bf16* wxr = WxG + (long)(j0 + ln) * 1024 + wkox + lk * 8;
#pragma unroll
            for (int ks = 0; ks < 8; ++ks) {
                short8v br  = ldg8(wxr + ks * 32);
                short8v bz  = ldg8(wxr + (1 << 20) + ks * 32);
                short8v bnn = ldg8(wxr + (2 << 20) + ks * 32);
                aR  = MFMA16(xcur[ks], br,  aR);
                aZ  = MFMA16(xcur[ks], bz,  aZ);
                aNI = MFMA16(xcur[ks], bnn, aNI);
            }
        }

        const bf16* bf_in = SEQ ? hin + (long)t * HB : hin + (long)(t & 1) * HB;
        const bf16* ha = bf_in + (long)(m0 + ln) * H_DIM + wkoh + lk * 8;
        short8v ah[8];
#pragma unroll
        for (int ks = 0; ks < 8; ++ks)
            ah[ks] = SEQ ? ldg8(ha + ks * 32) : ld_byp16(ha + ks * 32);

#pragma unroll
        for (int ks = 0; ks < 8; ++ks) {
            int o = whb0 + ks * 64;
            short8v br  = *(const short8v*)(smem + ((o        ) ^ swz));
            short8v bz  = *(const short8v*)(smem + ((o + 32768) ^ swz));
            short8v bnn = *(const short8v*)(smem + ((o + 65536) ^ swz));
            aR  = MFMA16(ah[ks], br,  aR);
            aZ  = MFMA16(ah[ks], bz,  aZ);
            aNH = MFMA16(ah[ks], bnn, aNH);
        }

        float* red = sm_red + (t & 1) * 4608;
#pragma unroll
        for (int a = 0; a < 4; ++a) {
            f32x4 v = (a == 0) ? aR : (a == 1) ? aZ : (a == 2) ? aNI : aNH;
            int base = ((w << 2) + a) * 288 + (lk * 4) * 18 + ln;
#pragma unroll
            for (int e = 0; e < 4; ++e)
                red[base + e * 18] = v[e];
        }
        __syncthreads();

        float sR = 0, sZ = 0, sNI = 0, sNH = 0;
#pragma unroll
        for (int w2 = 0; w2 < 4; ++w2) {
            int tb = (w2 << 2) * 288 + crow * 18 + ln;
            sR  += red[tb];
            sZ  += red[tb + 288];
            sNI += red[tb + 576];
            sNH += red[tb + 864];
        }
        float rr = 1.0f / (1.0f + __expf(-(sR + bias_r)));
        float zz = 1.0f / (1.0f + __expf(-(sZ + bias_z)));
        float xn = (sNI + bias_ni) + rr * (sNH + bias_nh);
        float nn = 2.0f / (1.0f + __expf(-2.0f * xn)) - 1.0f;
        float hv = (1.0f - zz) * nn + zz * hprev;
        hprev = hv;

        {
            bf16* wr = SEQ ? hout + (long)t * HB
                           : const_cast<bf16*>(hin) + (long)((t + 1) & 1) * HB;
            float ho = __shfl_xor(hv, 1);
            if ((ln & 1) == 0) {
                unsigned pk = (unsigned)f2bf_bits(hv)
                            | ((unsigned)f2bf_bits(ho) << 16);
                st_coh((unsigned*)(wr + (opos & ~1L)), pk);
            }
        }
        if (t == nsteps - 1 && f_final) f_final[opos] = hv;
        (void)flags;
    }
}

// ---------------------------------------------------------------------------
__global__ __launch_bounds__(1024) void head_kernel(
    const float* __restrict__ h2,
    const float* __restrict__ fc_W, const float* __restrict__ fc_b,
    const float* __restrict__ out_W, const float* __restrict__ out_b,
    float* __restrict__ y)
{
    __shared__ float acc_s[FC_DIM][B_DIM];
    const int b = threadIdx.x & 63;
    const int f = threadIdx.x >> 6;
    const float* wp = fc_W + (long)f * H_DIM;
    const float* hp = h2 + (long)b * H_DIM;
    float a = fc_b[f];
#pragma unroll 8
    for (int k = 0; k < H_DIM; ++k)
        a = fmaf(hp[k], wp[k], a);
    a = fmaxf(a, 0.0f);
    acc_s[f][b] = a * out_W[f];
    __syncthreads();
    if (threadIdx.x < 64) {
        float s = out_b[0];
#pragma unroll
        for (int f2 = 0; f2 < FC_DIM; ++f2) s += acc_s[f2][b];
        y[b] = s;
    }
}

// ---------------------------------------------------------------------------
extern "C" void kernel_launch(void* const* d_in, const int* in_sizes, int n_in,
                              void* d_out, int out_size, void* d_ws, size_t ws_size,
                              hipStream_t stream)
{
    const float* x      = (const float*)d_in[0];
    const float* e_Wih0 = (const float*)d_in[1];
    const float* e_Whh0 = (const float*)d_in[2];
    const float* e_bih0 = (const float*)d_in[3];
    const float* e_bhh0 = (const float*)d_in[4];
    const float* e_Wih1 = (const float*)d_in[5];
    const float* e_Whh1 = (const float*)d_in[6];
    const float* e_bih1 = (const float*)d_in[7];
    const float* e_bhh1 = (const float*)d_in[8];
    const float* d_Wih0 = (const float*)d_in[9];
    const float* d_Whh0 = (const float*)d_in[10];
    const float* d_bih0 = (const float*)d_in[11];
    const float* d_bhh0 = (const float*)d_in[12];
    const float* d_Wih1 = (const float*)d_in[13];
    const float* d_Whh1 = (const float*)d_in[14];
    const float* d_bih1 = (const float*)d_in[15];
    const float* d_bhh1 = (const float*)d_in[16];
    const float* fc_W   = (const float*)d_in[17];
    const float* fc_b   = (const float*)d_in[18];
    const float* out_W  = (const float*)d_in[19];
    const float* out_b  = (const float*)d_in[20];
    (void)in_sizes; (void)n_in; (void)out_size; (void)ws_size;

    char* p = (char*)d_ws;
    auto alloc = [&](size_t bytes) -> char* {
        char* r = p; p += (bytes + 255) & ~(size_t)255; return r;
    };
    bf16*  x_bf  = (bf16*)alloc((size_t)T_DIM * B_DIM * I_PAD * 2);
    bf16*  wih0e = (bf16*)alloc(3072ull * 128 * 2);
    bf16*  whh0e = (bf16*)alloc(3072ull * 1024 * 2);
    bf16*  wih1e = (bf16*)alloc(3072ull * 1024 * 2);
    bf16*  whh1e = (bf16*)alloc(3072ull * 1024 * 2);
    bf16*  wih0d = (bf16*)alloc(3072ull * 128 * 2);
    bf16*  whh0d = (bf16*)alloc(3072ull * 1024 * 2);
    bf16*  wih1d = (bf16*)alloc(3072ull * 1024 * 2);
    bf16*  whh1d = (bf16*)alloc(3072ull * 1024 * 2);
    bf16*  h1all = (bf16*)alloc(514ull * HB * 2);   // slots 0..513
    bf16*  h2pp  = (bf16*)alloc(2ull * HB * 2);
    float* hf1f  = (float*)alloc((size_t)HB * 4);
    float* hf2f  = (float*)alloc((size_t)HB * 4);
    float* hd1f  = (float*)alloc((size_t)HB * 4);
    float* hd2f  = (float*)alloc((size_t)HB * 4);
    unsigned* fl = (unsigned*)alloc(4096);          // [mh][bn][wave][layer]

    constexpr int SF = 98304 + 12288 + 2 * 17408;   // fused: 145408
    constexpr int RED = 2 * 4608 * 4;
    constexpr int S1  = 98304 + 12288 + RED;        // decoder cell 1
    constexpr int S2  = 98304 + RED;                // decoder cell 2
    (void)hipFuncSetAttribute((const void*)gru_fused,
                              hipFuncAttributeMaxDynamicSharedMemorySize, SF);
    (void)hipFuncSetAttribute((const void*)gru_pass<128, false, false>,
                              hipFuncAttributeMaxDynamicSharedMemorySize, S1);
    (void)hipFuncSetAttribute((const void*)gru_pass<1024, true, false>,
                              hipFuncAttributeMaxDynamicSharedMemorySize, S2);

    cvt_x_kernel<<<(T_DIM * B_DIM * I_PAD) / 256, 256, 0, stream>>>(x, x_bf);
    auto cvt = [&](const float* in, bf16* out, int kin, int kp) {
        long total = 3072L * kp;
        cvt_pad<<<(int)((total + 255) / 256), 256, 0, stream>>>(in, out, kin, kp, total);
    };
    cvt(e_Wih0, wih0e, 118, 128);
    cvt(e_Whh0, whh0e, 1024, 1024);
    cvt(e_Wih1, wih1e, 1024, 1024);
    cvt(e_Whh1, whh1e, 1024, 1024);
    cvt(d_Wih0, wih0d, 118, 128);
    cvt(d_Whh0, whh0d, 1024, 1024);
    cvt(d_Wih1, wih1d, 1024, 1024);
    cvt(d_Whh1, whh1d, 1024, 1024);

    // deterministic per-launch state
    hipMemsetAsync(h1all, 0, (size_t)HB * 2, stream);   // h1(-1) = 0
    hipMemsetAsync(h2pp,  0, 2ull * HB * 2, stream);    // h2(-1) = 0
    hipMemsetAsync(fl,    0, 4096, stream);

    // fused 2-layer encoder (both recurrences concurrent)
    gru_fused<<<256, 256, SF, stream>>>(
        x_bf, wih0e, whh0e, wih1e, whh1e,
        e_bih0, e_bhh0, e_bih1, e_bhh1,
        h1all, h2pp, hf1f, hf2f, fl);
    // h1(511) -> slot 512 (+ hf1f), h2(511) -> h2pp slot 0 (+ hf2f)

    // decoder cell 1: x = x[:,511,:], h = h1(511); writes bf16 out -> slot 513
    gru_pass<128, false, false><<<256, 256, S1, stream>>>(
        x_bf + 511L * B_DIM * I_PAD, 0, wih0d, whh0d, d_bih0, d_bhh0,
        h1all + 512L * HB, nullptr, hf1f, hd1f, 1, nullptr);

    // decoder cell 2: x = hd1 (slot 513), h = h2 (h2pp slot 0 / hf2f)
    gru_pass<1024, true, false><<<256, 256, S2, stream>>>(
        h1all + 513L * HB, 0, wih1d, whh1d, d_bih1, d_bhh1,
        h2pp, nullptr, hf2f, hd2f, 1, nullptr);

    head_kernel<<<1, 1024, 0, stream>>>(hd2f, fc_W, fc_b, out_W, out_b,
                                        (float*)d_out);
}

// Round 10
// 5387.438 us; speedup vs baseline: 1.4987x; 1.4987x over previous
//
#include <hip/hip_runtime.h>
#include <hip/hip_bf16.h>

#define H_DIM 1024
#define B_DIM 64
#define T_DIM 512
#define I_PAD 128
#define I_ORIG 118
#define FC_DIM 16
#define HB (B_DIM * H_DIM)

typedef __hip_bfloat16 bf16;
typedef __attribute__((ext_vector_type(8))) short short8v;
typedef __attribute__((ext_vector_type(4))) float f32x4;

#define MFMA16(a, b, c) __builtin_amdgcn_mfma_f32_16x16x32_bf16(a, b, c, 0, 0, 0)

__device__ __forceinline__ short8v ldg8(const bf16* p) {
    return *reinterpret_cast<const short8v*>(p);
}
// 16B load bypassing L1/L2 (fresh from coherence point)
__device__ __forceinline__ short8v ld_byp16(const bf16* p) {
    union { unsigned long long u[2]; short8v v; } r;
    const unsigned long long* q = reinterpret_cast<const unsigned long long*>(p);
    r.u[0] = __hip_atomic_load(q,     __ATOMIC_RELAXED, __HIP_MEMORY_SCOPE_AGENT);
    r.u[1] = __hip_atomic_load(q + 1, __ATOMIC_RELAXED, __HIP_MEMORY_SCOPE_AGENT);
    return r.v;
}
__device__ __forceinline__ unsigned short f2bf_bits(float f) {
    union { bf16 h; unsigned short s; } u;
    u.h = __float2bfloat16(f);
    return u.s;
}
__device__ __forceinline__ unsigned ld_coh(const unsigned* p) {
    return __hip_atomic_load(p, __ATOMIC_RELAXED, __HIP_MEMORY_SCOPE_AGENT);
}
__device__ __forceinline__ void st_coh(unsigned* p, unsigned v) {
    __hip_atomic_store(p, v, __ATOMIC_RELAXED, __HIP_MEMORY_SCOPE_AGENT);
}

// ---------------------------------------------------------------------------
// x[b][t][i] f32 -> x_bf[t][b][c] bf16 (c padded 118->128 with zeros)
// ---------------------------------------------------------------------------
__global__ __launch_bounds__(256) void cvt_x_kernel(
    const float* __restrict__ x, bf16* __restrict__ out)
{
    int idx  = blockIdx.x * 256 + threadIdx.x;
    int c    = idx & 127;
    int rest = idx >> 7;
    int b    = rest & 63;
    int t    = rest >> 6;
    float v  = (c < I_ORIG) ? x[((long)b * T_DIM + t) * I_ORIG + c] : 0.0f;
    out[idx] = __float2bfloat16(v);
}

__global__ __launch_bounds__(256) void cvt_pad(
    const float* __restrict__ in, bf16* __restrict__ out,
    int kin, int kp, long total)
{
    long idx = (long)blockIdx.x * 256 + threadIdx.x;
    if (idx >= total) return;
    int  c = (int)(idx % kp);
    long r = idx / kp;
    out[idx] = __float2bfloat16(c < kin ? in[r * kin + c] : 0.0f);
}

// ---------------------------------------------------------------------------
// MEGAROUND fused encoder. R7 topology verbatim: grid 256 x 256 (4 waves),
// bn = bid&63 (j-tile 16), grp = bid>>6 (batch-16 rows), wave = k-quarter.
// Round r (r = 0..513) computes h1(r) [r<=511] AND h2(r-2) [r>=2] in ONE
// sync round:
//   pre-poll:  L1 x-side MFMAs (LDS Wx1, xcur prefetched) and
//              L2 input-side MFMAs (global Wx2 x ah1p, where ah1p = h1(r-2)
//              fragments = LAST round's ah1 registers -- zero extra loads).
//   poll:      R7 per-wave flags, bare spin, tgt = r.
//   loads:     ah1 = h1all slot r (cached; write-once archive)  [r<=512]
//              ah2 = h2ring slot (r-1)&3 (bypass; 4-slot ring)  [r>=2]
//   MFMAs:     Whh1 (LDS) x ah1 ; Whh2 (global, XCD-L2 resident) x ah2.
//   reduce:    two static LDS buffers (L1, L2), SYNC_A / writes / SYNC_B /
//              reads (2 syncs per round; cross-round safety via SYNC_A).
//   combine:   R7 verbatim per layer, biases added post-reduce (once),
//              register-carried f32 hprev1/hprev2.
//   stores:    h1 -> h1all slot r+1 (sc1), h2 -> h2ring slot r&3 (sc1),
//              vmcnt(0), per-wave flag = r+1, then x prefetch + ah1p carry.
// Ring safety (M=4): writer at round r is flag-gated on round r-1 completion;
// the overwritten value (round r-4) was last read at round r-3. Bypass reads
// keep the ring coherent (no stale L2 lines).
// ---------------------------------------------------------------------------
__global__ __launch_bounds__(256, 1) void gru_mega(
    const bf16* __restrict__ x_bf,
    const bf16* __restrict__ Wx1,   // [3*1024][128]  -> LDS
    const bf16* __restrict__ Wh1,   // [3*1024][1024] -> LDS
    const bf16* __restrict__ Wx2,   // [3*1024][1024] global (L2-resident)
    const bf16* __restrict__ Wh2,   // [3*1024][1024] global (L2-resident)
    const float* __restrict__ bih1, const float* __restrict__ bhh1,
    const float* __restrict__ bih2, const float* __restrict__ bhh2,
    bf16* h1all,                    // slot s = h1(s-1); read slot r, write r+1
    bf16* h2ring,                   // 4 slots; round r writes h2(r-2) -> slot r&3
    float* hf1f, float* hf2f,
    unsigned* flags)
{
    extern __shared__ char smem[];
    constexpr int WH = 3 * 16 * 1024 * 2;     // 98304
    constexpr int WX = 3 * 16 * 128 * 2;      // 12288
    float* red1 = (float*)(smem + WH + WX);   // 4608 floats (16 tiles x 288)
    float* red2 = red1 + 4608;

    const int tid  = threadIdx.x;
    const int w    = tid >> 6;
    const int lane = tid & 63;
    const int ln   = lane & 15;
    const int lk   = lane >> 4;
    const int bid  = blockIdx.x;
    const int bn   = bid & 63;
    const int grp  = bid >> 6;
    const int j0   = bn * 16;
    const int m0   = grp * 16;
    const int j    = j0 + ln;

    // ---- stage Whh1 into LDS (swizzled rows of 2048B) + Wx1 (256B rows)
    for (int c = tid; c < WH / 16; c += 256) {
        int lin = c * 16;
        int row = lin >> 11;
        int wb  = lin & 2047;
        int g   = row >> 4, jj = row & 15;
        const bf16* src = Wh1 + ((long)(g * 1024 + j0 + jj) << 10) + (wb >> 1);
        *reinterpret_cast<short8v*>(smem + (lin ^ ((jj & 7) << 4))) = ldg8(src);
    }
    for (int c = tid; c < WX / 16; c += 256) {
        int lin = c * 16;
        int row = lin >> 8;
        int wb  = lin & 255;
        int g   = row >> 4, jj = row & 15;
        const bf16* src = Wx1 + (long)(g * 1024 + j0 + jj) * I_PAD + (wb >> 1);
        *reinterpret_cast<short8v*>(smem + WH + (lin ^ ((jj & 7) << 4))) = ldg8(src);
    }
    __syncthreads();

    const int wko  = w << 8;                       // hidden k-quarter
    const int wkox = w << 5;                       // x k-quarter (of 128)
    const int swz  = (ln & 7) << 4;
    const int whb0 = ln * 2048 + ((wko + lk * 8) << 1);

    const float b1r  = bih1[j] + bhh1[j];
    const float b1z  = bih1[j + 1024] + bhh1[j + 1024];
    const float b1ni = bih1[j + 2048];
    const float b1nh = bhh1[j + 2048];
    const float b2r  = bih2[j] + bhh2[j];
    const float b2z  = bih2[j + 1024] + bhh2[j + 1024];
    const float b2ni = bih2[j + 2048];
    const float b2nh = bhh2[j + 2048];

    const int  crow = (w << 2) | lk;
    const int  gm   = m0 + crow;
    const long opos = (long)gm * H_DIM + j;

    const bf16* wx2r = Wx2 + (long)j * 1024 + wko + lk * 8;
    const bf16* wh2r = Wh2 + (long)j * 1024 + wko + lk * 8;

    unsigned* myflag = flags + (grp << 8) + (bn << 2) + w;
    const unsigned* pollp = flags + (grp << 8) + (w << 6) + lane;

    float hprev1 = 0.0f, hprev2 = 0.0f;
    short8v ah1p[8];                    // h1(r-2) fragments (carried)
    short8v xcur;
    {
        const bf16* xr = x_bf + (long)(m0 + ln) * I_PAD + wkox + lk * 8;
        xcur = ldg8(xr);
    }

    const int NR = T_DIM + 2;           // 514 rounds
    for (int r = 0; r < NR; ++r) {
        const bool doL1  = (r < T_DIM);       // compute h1(r)
        const bool doL2  = (r >= 2);          // compute h2(r-2)
        const bool doLd1 = (r <= T_DIM);      // ah1 needed (L1 now / L2 next)

        f32x4 aR{0,0,0,0}, aZ{0,0,0,0}, aNI{0,0,0,0}, aNH{0,0,0,0};
        f32x4 cR{0,0,0,0}, cZ{0,0,0,0}, cNI{0,0,0,0}, cNH{0,0,0,0};

        // ---- pre-poll: L1 x-side (LDS Wx1)
        if (doL1) {
            int o = WH + ln * 256 + ((wkox + lk * 8) << 1);
            short8v br  = *(const short8v*)(smem + ((o       ) ^ swz));
            short8v bz  = *(const short8v*)(smem + ((o + 4096) ^ swz));
            short8v bnn = *(const short8v*)(smem + ((o + 8192) ^ swz));
            aR  = MFMA16(xcur, br,  aR);
            aZ  = MFMA16(xcur, bz,  aZ);
            aNI = MFMA16(xcur, bnn, aNI);
        }
        // ---- pre-poll: L2 input side (Wx2 x h1(r-2) = ah1p registers)
        if (doL2) {
#pragma unroll
            for (int ks = 0; ks < 8; ++ks) {
                short8v br  = ldg8(wx2r + ks * 32);
                short8v bz  = ldg8(wx2r + (1 << 20) + ks * 32);
                short8v bnn = ldg8(wx2r + (2 << 20) + ks * 32);
                cR  = MFMA16(ah1p[ks], br,  cR);
                cZ  = MFMA16(ah1p[ks], bz,  cZ);
                cNI = MFMA16(ah1p[ks], bnn, cNI);
            }
        }

        // ---- poll: this wave's 64 producer flags >= r (bare spin)
        if (r > 0) {
            const unsigned tgt = (unsigned)r;
            while (true) {
                unsigned fv = ld_coh(pollp);
                if (__all((int)(fv >= tgt))) break;
            }
            asm volatile("" ::: "memory");
        }

        // ---- A loads
        short8v ah1[8], ah2[8];
        if (doLd1) {
            const bf16* ha = h1all + (long)r * HB + (long)(m0 + ln) * H_DIM
                             + wko + lk * 8;
#pragma unroll
            for (int ks = 0; ks < 8; ++ks) ah1[ks] = ldg8(ha + ks * 32);
        }
        if (doL2) {
            const bf16* hb = h2ring + (long)((r - 1) & 3) * HB
                             + (long)(m0 + ln) * H_DIM + wko + lk * 8;
#pragma unroll
            for (int ks = 0; ks < 8; ++ks) ah2[ks] = ld_byp16(hb + ks * 32);
        }

        // ---- hidden MFMAs
        if (doL1) {
#pragma unroll
            for (int ks = 0; ks < 8; ++ks) {
                int o = whb0 + ks * 64;
                short8v br  = *(const short8v*)(smem + ((o        ) ^ swz));
                short8v bz  = *(const short8v*)(smem + ((o + 32768) ^ swz));
                short8v bnn = *(const short8v*)(smem + ((o + 65536) ^ swz));
                aR  = MFMA16(ah1[ks], br,  aR);
                aZ  = MFMA16(ah1[ks], bz,  aZ);
                aNH = MFMA16(ah1[ks], bnn, aNH);
            }
        }
        if (doL2) {
#pragma unroll
            for (int ks = 0; ks < 8; ++ks) {
                short8v br  = ldg8(wh2r + ks * 32);
                short8v bz  = ldg8(wh2r + (1 << 20) + ks * 32);
                short8v bnn = ldg8(wh2r + (2 << 20) + ks * 32);
                cR  = MFMA16(ah2[ks], br,  cR);
                cZ  = MFMA16(ah2[ks], bz,  cZ);
                cNH = MFMA16(ah2[ks], bnn, cNH);
            }
        }

        // ---- reduce (2 static buffers, 2 syncs)
        __syncthreads();      // SYNC_A: previous round's reads complete
        if (doL1) {
#pragma unroll
            for (int a = 0; a < 4; ++a) {
                f32x4 v = (a == 0) ? aR : (a == 1) ? aZ : (a == 2) ? aNI : aNH;
                int base = ((w << 2) + a) * 288 + (lk * 4) * 18 + ln;
#pragma unroll
                for (int e = 0; e < 4; ++e) red1[base + e * 18] = v[e];
            }
        }
        if (doL2) {
#pragma unroll
            for (int a = 0; a < 4; ++a) {
                f32x4 v = (a == 0) ? cR : (a == 1) ? cZ : (a == 2) ? cNI : cNH;
                int base = ((w << 2) + a) * 288 + (lk * 4) * 18 + ln;
#pragma unroll
                for (int e = 0; e < 4; ++e) red2[base + e * 18] = v[e];
            }
        }
        __syncthreads();      // SYNC_B: partials visible

        // ---- combine + stores
        if (doL1) {
            float sR = 0, sZ = 0, sNI = 0, sNH = 0;
#pragma unroll
            for (int w2 = 0; w2 < 4; ++w2) {
                int tb = (w2 << 2) * 288 + crow * 18 + ln;
                sR  += red1[tb];
                sZ  += red1[tb + 288];
                sNI += red1[tb + 576];
                sNH += red1[tb + 864];
            }
            float rr = 1.0f / (1.0f + __expf(-(sR + b1r)));
            float zz = 1.0f / (1.0f + __expf(-(sZ + b1z)));
            float xn = (sNI + b1ni) + rr * (sNH + b1nh);
            float nn = 2.0f / (1.0f + __expf(-2.0f * xn)) - 1.0f;
            float hv = (1.0f - zz) * nn + zz * hprev1;
            hprev1 = hv;
            bf16* dst = h1all + (long)(r + 1) * HB;
            float ho = __shfl_xor(hv, 1);
            if ((ln & 1) == 0) {
                unsigned pk = (unsigned)f2bf_bits(hv)
                            | ((unsigned)f2bf_bits(ho) << 16);
                st_coh((unsigned*)(dst + (opos & ~1L)), pk);
            }
            if (r == T_DIM - 1) hf1f[opos] = hv;
        }
        if (doL2) {
            float sR = 0, sZ = 0, sNI = 0, sNH = 0;
#pragma unroll
            for (int w2 = 0; w2 < 4; ++w2) {
                int tb = (w2 << 2) * 288 + crow * 18 + ln;
                sR  += red2[tb];
                sZ  += red2[tb + 288];
                sNI += red2[tb + 576];
                sNH += red2[tb + 864];
            }
            float rr = 1.0f / (1.0f + __expf(-(sR + b2r)));
            float zz = 1.0f / (1.0f + __expf(-(sZ + b2z)));
            float xn = (sNI + b2ni) + rr * (sNH + b2nh);
            float nn = 2.0f / (1.0f + __expf(-2.0f * xn)) - 1.0f;
            float hv = (1.0f - zz) * nn + zz * hprev2;
            hprev2 = hv;
            bf16* dst = h2ring + (long)(r & 3) * HB;
            float ho = __shfl_xor(hv, 1);
            if ((ln & 1) == 0) {
                unsigned pk = (unsigned)f2bf_bits(hv)
                            | ((unsigned)f2bf_bits(ho) << 16);
                st_coh((unsigned*)(dst + (opos & ~1L)), pk);
            }
            if (r == NR - 1) hf2f[opos] = hv;
        }

        // ---- ack stores, flag, then off-chain prefetch + register carry
        if (r + 1 < NR) {
            asm volatile("s_waitcnt vmcnt(0)" ::: "memory");
            if (lane == 0) st_coh(myflag, (unsigned)(r + 1));
        }
        if (r + 1 < T_DIM) {
            const bf16* xr = x_bf + (long)(r + 1) * (B_DIM * I_PAD)
                             + (long)(m0 + ln) * I_PAD + wkox + lk * 8;
            xcur = ldg8(xr);
        }
        if (doLd1) {
#pragma unroll
            for (int ks = 0; ks < 8; ++ks) ah1p[ks] = ah1[ks];
        }
    }
}

// ---------------------------------------------------------------------------
// Single-step GRU cell (decoder) — R7 kernel.
// ---------------------------------------------------------------------------
template<int WXK, bool WXG, bool SEQ>
__global__ __launch_bounds__(256, 1) void gru_pass(
    const bf16* __restrict__ xbase, long xstride,
    const bf16* __restrict__ WxG,
    const bf16* __restrict__ WhG,
    const float* __restrict__ bih, const float* __restrict__ bhh,
    const bf16* hin, bf16* hout,
    const float* f_init, float* f_final,
    int nsteps, unsigned* flags)
{
    extern __shared__ char smem[];
    constexpr int WH_BYTES = 3 * 16 * 1024 * 2;
    constexpr int WX_BYTES = WXG ? 0 : 3 * 16 * WXK * 2;
    float* sm_red = (float*)(smem + WH_BYTES + WX_BYTES);

    const int tid  = threadIdx.x;
    const int w    = tid >> 6;
    const int lane = tid & 63;
    const int ln   = lane & 15;
    const int lk   = lane >> 4;
    const int bid  = blockIdx.x;
    const int bn   = bid & 63;
    const int grp  = bid >> 6;
    const int j0   = bn * 16;
    const int m0   = grp * 16;
    const int j    = j0 + ln;

    for (int c = tid; c < WH_BYTES / 16; c += 256) {
        int lin = c * 16;
        int row = lin >> 11;
        int wb  = lin & 2047;
        int g   = row >> 4, jj = row & 15;
        const bf16* src = WhG + ((long)(g * 1024 + j0 + jj) << 10) + (wb >> 1);
        *reinterpret_cast<short8v*>(smem + (lin ^ ((jj & 7) << 4))) = ldg8(src);
    }
    if constexpr (!WXG) {
        for (int c = tid; c < WX_BYTES / 16; c += 256) {
            int lin = c * 16;
            int row = lin / (WXK * 2);
            int wb  = lin % (WXK * 2);
            int g   = row >> 4, jj = row & 15;
            const bf16* src = WxG + (long)(g * 1024 + j0 + jj) * WXK + (wb >> 1);
            *reinterpret_cast<short8v*>(smem + WH_BYTES + (lin ^ ((jj & 7) << 4))) = ldg8(src);
        }
    }
    __syncthreads();

    const int wkoh = w << 8;
    const int wkox = (WXK == 128) ? (w << 5) : (w << 8);
    const int swz  = (ln & 7) << 4;
    const int whb0 = ln * 2048 + ((wkoh + lk * 8) << 1);

    const float bias_r  = bih[j] + bhh[j];
    const float bias_z  = bih[j + H_DIM] + bhh[j + H_DIM];
    const float bias_ni = bih[j + 2 * H_DIM];
    const float bias_nh = bhh[j + 2 * H_DIM];

    const int  crow = (w << 2) | lk;
    const int  gm   = m0 + crow;
    const long opos = (long)gm * H_DIM + j;

    float hprev = f_init ? f_init[opos] : 0.0f;

    constexpr int NKX = (WXK == 128) ? 1 : 8;
    short8v xcur[NKX];
    {
        const bf16* xr = xbase + (long)(m0 + ln) * WXK + wkox + lk * 8;
#pragma unroll
        for (int ks = 0; ks < NKX; ++ks) xcur[ks] = ldg8(xr + ks * 32);
    }

    for (int t = 0; t < nsteps; ++t) {
        f32x4 aR{0,0,0,0}, aZ{0,0,0,0}, aNI{0,0,0,0}, aNH{0,0,0,0};

        if constexpr (WXK == 128) {
            int o = WH_BYTES + ln * 256 + ((wkox + lk * 8) << 1);
            short8v br  = *(const short8v*)(smem + ((o       ) ^ swz));
            short8v bz  = *(const short8v*)(smem + ((o + 4096) ^ swz));
            short8v bnn = *(const short8v*)(smem + ((o + 8192) ^ swz));
            aR  = MFMA16(xcur[0], br,  aR);
            aZ  = MFMA16(xcur[0], bz,  aZ);
            aNI = MFMA16(xcur[0], bnn, aNI);
        } else {
            const bf16* wxr = WxG + (long)(j0 + ln) * 1024 + wkox + lk * 8;
#pragma unroll
            for (int ks = 0; ks < 8; ++ks) {
                short8v br  = ldg8(wxr + ks * 32);
                short8v bz  = ldg8(wxr + (1 << 20) + ks * 32);
                short8v bnn = ldg8(wxr + (2 << 20) + ks * 32);
                aR  = MFMA16(xcur[ks], br,  aR);
                aZ  = MFMA16(xcur[ks], bz,  aZ);
                aNI = MFMA16(xcur[ks], bnn, aNI);
            }
        }

        const bf16* bf_in = SEQ ? hin + (long)t * HB : hin + (long)(t & 1) * HB;
        const bf16* ha = bf_in + (long)(m0 + ln) * H_DIM + wkoh + lk * 8;
        short8v ah[8];
#pragma unroll
        for (int ks = 0; ks < 8; ++ks)
            ah[ks] = SEQ ? ldg8(ha + ks * 32) : ld_byp16(ha + ks * 32);

#pragma unroll
        for (int ks = 0; ks < 8; ++ks) {
            int o = whb0 + ks * 64;
            short8v br  = *(const short8v*)(smem + ((o        ) ^ swz));
            short8v bz  = *(const short8v*)(smem + ((o + 32768) ^ swz));
            short8v bnn = *(const short8v*)(smem + ((o + 65536) ^ swz));
            aR  = MFMA16(ah[ks], br,  aR);
            aZ  = MFMA16(ah[ks], bz,  aZ);
            aNH = MFMA16(ah[ks], bnn, aNH);
        }

        float* red = sm_red + (t & 1) * 4608;
#pragma unroll
        for (int a = 0; a < 4; ++a) {
            f32x4 v = (a == 0) ? aR : (a == 1) ? aZ : (a == 2) ? aNI : aNH;
            int base = ((w << 2) + a) * 288 + (lk * 4) * 18 + ln;
#pragma unroll
            for (int e = 0; e < 4; ++e)
                red[base + e * 18] = v[e];
        }
        __syncthreads();

        float sR = 0, sZ = 0, sNI = 0, sNH = 0;
#pragma unroll
        for (int w2 = 0; w2 < 4; ++w2) {
            int tb = (w2 << 2) * 288 + crow * 18 + ln;
            sR  += red[tb];
            sZ  += red[tb + 288];
            sNI += red[tb + 576];
            sNH += red[tb + 864];
        }
        float rr = 1.0f / (1.0f + __expf(-(sR + bias_r)));
        float zz = 1.0f / (1.0f + __expf(-(sZ + bias_z)));
        float xn = (sNI + bias_ni) + rr * (sNH + bias_nh);
        float nn = 2.0f / (1.0f + __expf(-2.0f * xn)) - 1.0f;
        float hv = (1.0f - zz) * nn + zz * hprev;
        hprev = hv;

        {
            bf16* wr = SEQ ? hout + (long)t * HB
                           : const_cast<bf16*>(hin) + (long)((t + 1) & 1) * HB;
            float ho = __shfl_xor(hv, 1);
            if ((ln & 1) == 0) {
                unsigned pk = (unsigned)f2bf_bits(hv)
                            | ((unsigned)f2bf_bits(ho) << 16);
                st_coh((unsigned*)(wr + (opos & ~1L)), pk);
            }
        }
        if (t == nsteps - 1 && f_final) f_final[opos] = hv;
        (void)flags;
    }
}

// ---------------------------------------------------------------------------
__global__ __launch_bounds__(1024) void head_kernel(
    const float* __restrict__ h2,
    const float* __restrict__ fc_W, const float* __restrict__ fc_b,
    const float* __restrict__ out_W, const float* __restrict__ out_b,
    float* __restrict__ y)
{
    __shared__ float acc_s[FC_DIM][B_DIM];
    const int b = threadIdx.x & 63;
    const int f = threadIdx.x >> 6;
    const float* wp = fc_W + (long)f * H_DIM;
    const float* hp = h2 + (long)b * H_DIM;
    float a = fc_b[f];
#pragma unroll 8
    for (int k = 0; k < H_DIM; ++k)
        a = fmaf(hp[k], wp[k], a);
    a = fmaxf(a, 0.0f);
    acc_s[f][b] = a * out_W[f];
    __syncthreads();
    if (threadIdx.x < 64) {
        float s = out_b[0];
#pragma unroll
        for (int f2 = 0; f2 < FC_DIM; ++f2) s += acc_s[f2][b];
        y[b] = s;
    }
}

// ---------------------------------------------------------------------------
extern "C" void kernel_launch(void* const* d_in, const int* in_sizes, int n_in,
                              void* d_out, int out_size, void* d_ws, size_t ws_size,
                              hipStream_t stream)
{
    const float* x      = (const float*)d_in[0];
    const float* e_Wih0 = (const float*)d_in[1];
    const float* e_Whh0 = (const float*)d_in[2];
    const float* e_bih0 = (const float*)d_in[3];
    const float* e_bhh0 = (const float*)d_in[4];
    const float* e_Wih1 = (const float*)d_in[5];
    const float* e_Whh1 = (const float*)d_in[6];
    const float* e_bih1 = (const float*)d_in[7];
    const float* e_bhh1 = (const float*)d_in[8];
    const float* d_Wih0 = (const float*)d_in[9];
    const float* d_Whh0 = (const float*)d_in[10];
    const float* d_bih0 = (const float*)d_in[11];
    const float* d_bhh0 = (const float*)d_in[12];
    const float* d_Wih1 = (const float*)d_in[13];
    const float* d_Whh1 = (const float*)d_in[14];
    const float* d_bih1 = (const float*)d_in[15];
    const float* d_bhh1 = (const float*)d_in[16];
    const float* fc_W   = (const float*)d_in[17];
    const float* fc_b   = (const float*)d_in[18];
    const float* out_W  = (const float*)d_in[19];
    const float* out_b  = (const float*)d_in[20];
    (void)in_sizes; (void)n_in; (void)out_size; (void)ws_size;

    char* p = (char*)d_ws;
    auto alloc = [&](size_t bytes) -> char* {
        char* r = p; p += (bytes + 255) & ~(size_t)255; return r;
    };
    bf16*  x_bf  = (bf16*)alloc((size_t)T_DIM * B_DIM * I_PAD * 2);
    bf16*  wih0e = (bf16*)alloc(3072ull * 128 * 2);
    bf16*  whh0e = (bf16*)alloc(3072ull * 1024 * 2);
    bf16*  wih1e = (bf16*)alloc(3072ull * 1024 * 2);
    bf16*  whh1e = (bf16*)alloc(3072ull * 1024 * 2);
    bf16*  wih0d = (bf16*)alloc(3072ull * 128 * 2);
    bf16*  whh0d = (bf16*)alloc(3072ull * 1024 * 2);
    bf16*  wih1d = (bf16*)alloc(3072ull * 1024 * 2);
    bf16*  whh1d = (bf16*)alloc(3072ull * 1024 * 2);
    bf16*  h1all = (bf16*)alloc(514ull * HB * 2);   // slots 0..513
    bf16*  h2rg  = (bf16*)alloc(4ull * HB * 2);     // 4-slot ring
    bf16*  hd1b  = (bf16*)alloc((size_t)HB * 2);
    bf16*  hd2b  = (bf16*)alloc((size_t)HB * 2);
    float* hf1f  = (float*)alloc((size_t)HB * 4);
    float* hf2f  = (float*)alloc((size_t)HB * 4);
    float* hd1f  = (float*)alloc((size_t)HB * 4);
    float* hd2f  = (float*)alloc((size_t)HB * 4);
    unsigned* fl = (unsigned*)alloc(4096);          // 4 grp x 64 bn x 4 w

    constexpr int RED = 2 * 4608 * 4;               // 36864
    constexpr int SM  = 98304 + 12288 + RED;        // mega: 147456
    constexpr int S1  = 98304 + 12288 + RED;        // decoder cell 1
    constexpr int S2  = 98304 + RED;                // decoder cell 2
    (void)hipFuncSetAttribute((const void*)gru_mega,
                              hipFuncAttributeMaxDynamicSharedMemorySize, SM);
    (void)hipFuncSetAttribute((const void*)gru_pass<128, false, true>,
                              hipFuncAttributeMaxDynamicSharedMemorySize, S1);
    (void)hipFuncSetAttribute((const void*)gru_pass<1024, true, false>,
                              hipFuncAttributeMaxDynamicSharedMemorySize, S2);

    cvt_x_kernel<<<(T_DIM * B_DIM * I_PAD) / 256, 256, 0, stream>>>(x, x_bf);
    auto cvt = [&](const float* in, bf16* out, int kin, int kp) {
        long total = 3072L * kp;
        cvt_pad<<<(int)((total + 255) / 256), 256, 0, stream>>>(in, out, kin, kp, total);
    };
    cvt(e_Wih0, wih0e, 118, 128);
    cvt(e_Whh0, whh0e, 1024, 1024);
    cvt(e_Wih1, wih1e, 1024, 1024);
    cvt(e_Whh1, whh1e, 1024, 1024);
    cvt(d_Wih0, wih0d, 118, 128);
    cvt(d_Whh0, whh0d, 1024, 1024);
    cvt(d_Wih1, wih1d, 1024, 1024);
    cvt(d_Whh1, whh1d, 1024, 1024);

    // deterministic per-launch state
    hipMemsetAsync(h1all, 0, (size_t)HB * 2, stream);       // h1(-1) = 0
    hipMemsetAsync(h2rg,  0, 2ull * HB * 2, stream);        // h2(-2),h2(-1) = 0
    hipMemsetAsync(fl,    0, 4096, stream);

    // fused encoder: h1(t) and h2(t-2) per round, 514 rounds
    gru_mega<<<256, 256, SM, stream>>>(
        x_bf, wih0e, whh0e, wih1e, whh1e,
        e_bih0, e_bhh0, e_bih1, e_bhh1,
        h1all, h2rg, hf1f, hf2f, fl);
    // h1(511) -> h1all slot 512 (+ hf1f); h2(511) -> h2rg slot 513&3=1 (+ hf2f)

    // decoder cell 1: x = x[:,511,:], h = h1(511) (cached write-once slot)
    gru_pass<128, false, true><<<256, 256, S1, stream>>>(
        x_bf + 511L * B_DIM * I_PAD, 0, wih0d, whh0d, d_bih0, d_bhh0,
        h1all + 512L * HB, hd1b, hf1f, hd1f, 1, nullptr);

    // decoder cell 2: x = hd1, h = h2(511) (ring slot 1; bypass reads)
    gru_pass<1024, true, false><<<256, 256, S2, stream>>>(
        hd1b, 0, wih1d, whh1d, d_bih1, d_bhh1,
        h2rg + 1L * HB, hd2b, hf2f, hd2f, 1, nullptr);

    head_kernel<<<1, 1024, 0, stream>>>(hd2f, fc_W, fc_b, out_W, out_b,
                                        (float*)d_out);
}